// Round 4
// baseline (43.389 us; speedup 1.0000x reference)
//
#include <hip/hip_runtime.h>

// PrRoI pooling (exact bilinear-integral) for feat [64,256,72,72] f32,
// bb [64,4] (x,y,w,h image coords, stride 16), out [64,256,4,4] f32.
//
// Separable weights: out[p][q] = (1/area) * sum_w gx[q][w] * sum_h gy[p][h] * f[h][w].
// Block = 256 threads (4 waves) = one n x 8 channels; grid 2048 = 8 blocks/CU
// (32 waves/CU, full occupancy; __launch_bounds__(256,8) caps VGPR at 64).
//   phase 1: each wave does 2 channels; lane = (col 0..31, row-parity 0..1);
//            h-loop unrolled x4 with predicated (clamped-address, zero-weight)
//            rows instead of a serial tail -> 8 global loads in flight.
//   phase 2: LDS transpose-reduce: thread t<128 owns output (ch,p,q) and dots
//            s_row[64] with gx[q][64] via float4 LDS reads.

constexpr int N_ = 64;
constexpr int C_ = 256;
constexpr int H_ = 72;
constexpr int W_ = 72;
constexpr int HW_ = H_ * W_;
constexpr int CPW = 2;               // channels per wave
constexpr int NW  = 4;               // waves per block
constexpr int CPB = CPW * NW;        // 8 channels per block
constexpr int SPAD = 68;             // padded row length (floats)

__device__ __forceinline__ float Gfun(float u) {
    // Antiderivative of max(0, 1-|u|), clipped so G(-1)=0, G(1)=1.
    u = fminf(1.0f, fmaxf(-1.0f, u));
    return (u <= 0.0f) ? (0.5f * (u + 1.0f) * (u + 1.0f))
                       : (1.0f - 0.5f * (1.0f - u) * (1.0f - u));
}

__global__ __launch_bounds__(256, 8)
void prroi_kernel(const float* __restrict__ feat,
                  const float* __restrict__ bb,
                  float* __restrict__ out) {
    __shared__ float gy_lds[32][4];               // rows j0..j0+31 (zero past j1)
    __shared__ float gx_lds[4][SPAD];
    __shared__ float s_lds[CPB * 4][SPAD];        // [(ch*4+p)][lane]

    const int bid = blockIdx.x;
    const int n   = bid >> 5;          // 32 channel-groups per n
    const int cg  = bid & 31;
    const int tid = (int)threadIdx.x;
    const int w      = tid >> 6;
    const int lane   = tid & 63;
    const int coll   = lane & 31;      // column offset within ROI window
    const int parity = lane >> 5;      // row parity this lane handles

    const float bx = bb[n*4+0], by = bb[n*4+1], bw = bb[n*4+2], bh = bb[n*4+3];
    const float inv_s = 1.0f / 16.0f;
    const float x1 = bx*inv_s,        y1 = by*inv_s;
    const float x2 = (bx+bw)*inv_s,   y2 = (by+bh)*inv_s;
    const float binw = (x2-x1)*0.25f, binh = (y2-y1)*0.25f;

    // Support of the bilinear weights: i in (x1-1, x2+1); integer span <= 30.
    const int i0 = max((int)ceilf(x1 - 1.0f), 0);
    const int i1 = min((int)floorf(x2 + 1.0f), W_-1);
    const int j0 = max((int)ceilf(y1 - 1.0f), 0);
    const int j1 = min((int)floorf(y2 + 1.0f), H_-1);

    // ---- weight tables (once per block) ----
    if (tid < 128) {                   // 32 rows x 4 bins
        const int r = tid >> 2, p = tid & 3;
        const int h = j0 + r;
        float v = 0.0f;
        if (h <= j1) {
            const float a = y1 + (float)p * binh, b = a + binh;
            v = Gfun(b - (float)h) - Gfun(a - (float)h);
        }
        gy_lds[r][p] = v;
    }
    {                                  // gx duplicated across both parities
        const int q = tid >> 6, l = tid & 63;
        const int col = i0 + (l & 31);
        float v = 0.0f;
        if (col <= i1) {
            const float a = x1 + (float)q * binw, b = a + binw;
            v = Gfun(b - (float)col) - Gfun(a - (float)col);
        }
        gx_lds[q][l] = v;
    }
    __syncthreads();

    // ---- phase 1: row-weighted column sums, 2 channels per wave ----
    // Inactive columns / past-the-end rows load clamped (valid) addresses;
    // their contributions are zeroed by gx == 0 (phase 2) or gy == 0 (here).
    const int colc = min(i0 + coll, W_-1);
    const float* fb = feat + (size_t)(n*C_ + cg*CPB + w*CPW) * HW_;
    float s[CPW][4] = {};
    for (int h = j0 + parity; h <= j1; h += 8) {
        // rows h, h+2, h+4, h+6; gy index max = 31 (see span bound), addresses
        // clamped to the last image row (dup loads = cache hits).
        const int a0 = min(h    , H_-1)*W_ + colc;
        const int a1 = min(h + 2, H_-1)*W_ + colc;
        const int a2 = min(h + 4, H_-1)*W_ + colc;
        const int a3 = min(h + 6, H_-1)*W_ + colc;
        float f[CPW][4];
        #pragma unroll
        for (int c = 0; c < CPW; ++c) {
            const float* fc = fb + c*HW_;
            f[c][0] = fc[a0]; f[c][1] = fc[a1]; f[c][2] = fc[a2]; f[c][3] = fc[a3];
        }
        const int r = h - j0;
        const float4 gy0 = *reinterpret_cast<const float4*>(&gy_lds[r    ][0]);
        const float4 gy1 = *reinterpret_cast<const float4*>(&gy_lds[r + 2][0]);
        const float4 gy2 = *reinterpret_cast<const float4*>(&gy_lds[r + 4][0]);
        const float4 gy3 = *reinterpret_cast<const float4*>(&gy_lds[r + 6][0]);
        #pragma unroll
        for (int c = 0; c < CPW; ++c) {
            s[c][0] = fmaf(gy0.x, f[c][0], s[c][0]);
            s[c][1] = fmaf(gy0.y, f[c][0], s[c][1]);
            s[c][2] = fmaf(gy0.z, f[c][0], s[c][2]);
            s[c][3] = fmaf(gy0.w, f[c][0], s[c][3]);
            s[c][0] = fmaf(gy1.x, f[c][1], s[c][0]);
            s[c][1] = fmaf(gy1.y, f[c][1], s[c][1]);
            s[c][2] = fmaf(gy1.z, f[c][1], s[c][2]);
            s[c][3] = fmaf(gy1.w, f[c][1], s[c][3]);
            s[c][0] = fmaf(gy2.x, f[c][2], s[c][0]);
            s[c][1] = fmaf(gy2.y, f[c][2], s[c][1]);
            s[c][2] = fmaf(gy2.z, f[c][2], s[c][2]);
            s[c][3] = fmaf(gy2.w, f[c][2], s[c][3]);
            s[c][0] = fmaf(gy3.x, f[c][3], s[c][0]);
            s[c][1] = fmaf(gy3.y, f[c][3], s[c][1]);
            s[c][2] = fmaf(gy3.z, f[c][3], s[c][2]);
            s[c][3] = fmaf(gy3.w, f[c][3], s[c][3]);
        }
    }
    #pragma unroll
    for (int c = 0; c < CPW; ++c)
        #pragma unroll
        for (int p = 0; p < 4; ++p)
            s_lds[(w*CPW + c)*4 + p][lane] = s[c][p];   // 64 consecutive cols: conflict-free
    __syncthreads();

    // ---- phase 2: one output per thread (tid < 128); out offset == tid ----
    if (tid < CPB * 16) {
        const int q = tid & 3;
        const int rowi = tid >> 2;               // (ch*4 + p), 0..31
        const float* srow = &s_lds[rowi][0];
        const float* gxr  = &gx_lds[q][0];
        float acc = 0.0f;
        #pragma unroll
        for (int i = 0; i < 16; ++i) {
            const float4 sv = *reinterpret_cast<const float4*>(srow + i*4);
            const float4 gv = *reinterpret_cast<const float4*>(gxr  + i*4);
            acc += sv.x*gv.x + sv.y*gv.y + sv.z*gv.z + sv.w*gv.w;
        }
        const float area = fmaxf(binw * binh, 0.0f);
        const float inv  = (area > 0.0f) ? (1.0f / fmaxf(area, 1e-12f)) : 0.0f;
        out[(size_t)(n*C_ + cg*CPB) * 16 + tid] = acc * inv;
    }
}

extern "C" void kernel_launch(void* const* d_in, const int* in_sizes, int n_in,
                              void* d_out, int out_size, void* d_ws, size_t ws_size,
                              hipStream_t stream) {
    const float* feat = (const float*)d_in[0];
    const float* bb   = (const float*)d_in[1];
    float* outp       = (float*)d_out;
    prroi_kernel<<<dim3(N_ * (C_ / CPB)), dim3(256), 0, stream>>>(feat, bb, outp);
}

// Round 5
// 18.613 us; speedup vs baseline: 2.3311x; 2.3311x over previous
//
#include <hip/hip_runtime.h>

// PrRoI pooling (exact bilinear-integral) for feat [64,256,72,72] f32,
// bb [64,4] (x,y,w,h image coords, stride 16), out [64,256,4,4] f32.
//
// Separable weights: out[p][q] = (1/area) * sum_w gx[q][w] * sum_h gy[p][h] * f[h][w].
// Block = 256 threads (4 waves) = one n x 16 channels; grid 1024.
//   phase 1: each wave does 4 channels; lane = (col 0..31, row-parity 0..1);
//            h-loop unrolled x4 (rows h, h+2, h+4, h+6) with predication:
//            addresses clamp to j1 (dup loads = L1 hits, no extra HBM lines),
//            weights come from a zero-padded gy table (40 rows) -> no tail
//            loop, 16 independent global loads in flight per iteration.
//   phase 2: LDS transpose-reduce: thread t owns output (ch,p,q) = t and dots
//            s_row[64] with gx[q][64] via float4 LDS reads (rows padded to 68
//            floats -> at most 2-way bank aliasing, free on CDNA4).
//
// NOTE: no __launch_bounds__ min-wave cap — forcing 64 VGPRs spills the
// inner loop (round-4 regression: 19.3 -> 43.4 us).

constexpr int N_ = 64;
constexpr int C_ = 256;
constexpr int H_ = 72;
constexpr int W_ = 72;
constexpr int HW_ = H_ * W_;
constexpr int CPW = 4;               // channels per wave
constexpr int NW  = 4;               // waves per block
constexpr int CPB = CPW * NW;        // 16 channels per block
constexpr int SPAD = 68;             // padded row length (floats)
constexpr int GYR = 40;              // gy rows incl. zero padding (max r+6 = 36)

__device__ __forceinline__ float Gfun(float u) {
    // Antiderivative of max(0, 1-|u|), clipped so G(-1)=0, G(1)=1.
    u = fminf(1.0f, fmaxf(-1.0f, u));
    return (u <= 0.0f) ? (0.5f * (u + 1.0f) * (u + 1.0f))
                       : (1.0f - 0.5f * (1.0f - u) * (1.0f - u));
}

__global__ __launch_bounds__(256)
void prroi_kernel(const float* __restrict__ feat,
                  const float* __restrict__ bb,
                  float* __restrict__ out) {
    __shared__ float gy_lds[GYR][4];              // rows j0.., zero past j1
    __shared__ float gx_lds[4][SPAD];
    __shared__ float s_lds[CPB * 4][SPAD];        // [(ch*4+p)][lane]

    const int bid = blockIdx.x;
    const int n   = bid >> 4;          // 16 channel-groups per n
    const int cg  = bid & 15;
    const int tid = (int)threadIdx.x;
    const int w      = tid >> 6;
    const int lane   = tid & 63;
    const int coll   = lane & 31;      // column offset within ROI window
    const int parity = lane >> 5;      // row parity this lane handles

    const float bx = bb[n*4+0], by = bb[n*4+1], bw = bb[n*4+2], bh = bb[n*4+3];
    const float inv_s = 1.0f / 16.0f;
    const float x1 = bx*inv_s,        y1 = by*inv_s;
    const float x2 = (bx+bw)*inv_s,   y2 = (by+bh)*inv_s;
    const float binw = (x2-x1)*0.25f, binh = (y2-y1)*0.25f;

    // Support of the bilinear weights: i in (x1-1, x2+1); integer span <= 30.
    const int i0 = max((int)ceilf(x1 - 1.0f), 0);
    const int i1 = min((int)floorf(x2 + 1.0f), W_-1);
    const int j0 = max((int)ceilf(y1 - 1.0f), 0);
    const int j1 = min((int)floorf(y2 + 1.0f), H_-1);

    // ---- weight tables (once per block) ----
    if (tid < GYR * 4) {               // 40 rows x 4 bins (zeros past j1)
        const int r = tid >> 2, p = tid & 3;
        const int h = j0 + r;
        float v = 0.0f;
        if (h <= j1) {
            const float a = y1 + (float)p * binh, b = a + binh;
            v = Gfun(b - (float)h) - Gfun(a - (float)h);
        }
        gy_lds[r][p] = v;
    }
    {                                  // gx duplicated across both parities
        const int q = tid >> 6, l = tid & 63;
        const int col = i0 + (l & 31);
        float v = 0.0f;
        if (col <= i1) {
            const float a = x1 + (float)q * binw, b = a + binw;
            v = Gfun(b - (float)col) - Gfun(a - (float)col);
        }
        gx_lds[q][l] = v;
    }
    __syncthreads();

    // ---- phase 1: row-weighted column sums, 4 channels per wave ----
    // Inactive columns / past-j1 rows use clamped (already-fetched) addresses;
    // their contributions are zeroed by gx == 0 (phase 2) or gy == 0 (here).
    const int colc = min(i0 + coll, W_-1);
    const float* fb = feat + (size_t)(n*C_ + cg*CPB + w*CPW) * HW_;
    float s[CPW][4] = {};
    for (int h = j0 + parity; h <= j1; h += 8) {
        // rows h, h+2, h+4, h+6; addresses clamp to j1 (same line, L1 hit),
        // weights past j1 are zeros from the padded gy table.
        const int a0 = h*W_ + colc;                 // h <= j1 by loop condition
        const int a1 = min(h + 2, j1)*W_ + colc;
        const int a2 = min(h + 4, j1)*W_ + colc;
        const int a3 = min(h + 6, j1)*W_ + colc;
        float f[CPW][4];
        #pragma unroll
        for (int c = 0; c < CPW; ++c) {
            const float* fc = fb + c*HW_;
            f[c][0] = fc[a0]; f[c][1] = fc[a1]; f[c][2] = fc[a2]; f[c][3] = fc[a3];
        }
        const int r = h - j0;
        const float4 gy0 = *reinterpret_cast<const float4*>(&gy_lds[r    ][0]);
        const float4 gy1 = *reinterpret_cast<const float4*>(&gy_lds[r + 2][0]);
        const float4 gy2 = *reinterpret_cast<const float4*>(&gy_lds[r + 4][0]);
        const float4 gy3 = *reinterpret_cast<const float4*>(&gy_lds[r + 6][0]);
        #pragma unroll
        for (int c = 0; c < CPW; ++c) {
            s[c][0] = fmaf(gy0.x, f[c][0], s[c][0]);
            s[c][1] = fmaf(gy0.y, f[c][0], s[c][1]);
            s[c][2] = fmaf(gy0.z, f[c][0], s[c][2]);
            s[c][3] = fmaf(gy0.w, f[c][0], s[c][3]);
            s[c][0] = fmaf(gy1.x, f[c][1], s[c][0]);
            s[c][1] = fmaf(gy1.y, f[c][1], s[c][1]);
            s[c][2] = fmaf(gy1.z, f[c][1], s[c][2]);
            s[c][3] = fmaf(gy1.w, f[c][1], s[c][3]);
            s[c][0] = fmaf(gy2.x, f[c][2], s[c][0]);
            s[c][1] = fmaf(gy2.y, f[c][2], s[c][1]);
            s[c][2] = fmaf(gy2.z, f[c][2], s[c][2]);
            s[c][3] = fmaf(gy2.w, f[c][2], s[c][3]);
            s[c][0] = fmaf(gy3.x, f[c][3], s[c][0]);
            s[c][1] = fmaf(gy3.y, f[c][3], s[c][1]);
            s[c][2] = fmaf(gy3.z, f[c][3], s[c][2]);
            s[c][3] = fmaf(gy3.w, f[c][3], s[c][3]);
        }
    }
    #pragma unroll
    for (int c = 0; c < CPW; ++c)
        #pragma unroll
        for (int p = 0; p < 4; ++p)
            s_lds[(w*CPW + c)*4 + p][lane] = s[c][p];   // 64 consecutive cols: conflict-free
    __syncthreads();

    // ---- phase 2: one output per thread; out offset == tid ----
    const int q = tid & 3;
    const int rowi = tid >> 2;                   // (ch*4 + p), 0..63
    const float* srow = &s_lds[rowi][0];
    const float* gxr  = &gx_lds[q][0];
    float acc = 0.0f;
    #pragma unroll
    for (int i = 0; i < 16; ++i) {
        const float4 sv = *reinterpret_cast<const float4*>(srow + i*4);
        const float4 gv = *reinterpret_cast<const float4*>(gxr  + i*4);
        acc += sv.x*gv.x + sv.y*gv.y + sv.z*gv.z + sv.w*gv.w;
    }
    const float area = fmaxf(binw * binh, 0.0f);
    const float inv  = (area > 0.0f) ? (1.0f / fmaxf(area, 1e-12f)) : 0.0f;
    out[(size_t)(n*C_ + cg*CPB) * 16 + tid] = acc * inv;
}

extern "C" void kernel_launch(void* const* d_in, const int* in_sizes, int n_in,
                              void* d_out, int out_size, void* d_ws, size_t ws_size,
                              hipStream_t stream) {
    const float* feat = (const float*)d_in[0];
    const float* bb   = (const float*)d_in[1];
    float* outp       = (float*)d_out;
    prroi_kernel<<<dim3(N_ * (C_ / CPB)), dim3(256), 0, stream>>>(feat, bb, outp);
}

// Round 6
// 17.019 us; speedup vs baseline: 2.5495x; 1.0937x over previous
//
#include <hip/hip_runtime.h>

// PrRoI pooling (exact bilinear-integral) for feat [64,256,72,72] f32,
// bb [64,4] (x,y,w,h image coords, stride 16), out [64,256,4,4] f32.
//
// Separable weights: out[p][q] = (1/area) * sum_w gx[q][w] * sum_h gy[p][h] * f[h][w].
// Block = 256 threads (4 waves) = one n x 8 channels; grid 2048 (8 blocks/CU,
// fine-grained for dynamic load balancing across variable ROI sizes).
// n = bid & 63 so consecutively-dispatched blocks carry different ROI sizes.
//   phase 1: each wave does 2 channels; lane = (col 0..31, row-parity 0..1);
//            h-loop unrolled x4 (rows h, h+2, h+4, h+6) with predication:
//            row addresses clamp to j1, column addresses clamp to i1 (both
//            within lines the wave already fetches -> no extra HBM traffic),
//            weights from zero-padded tables -> no tail loop.
//   phase 2: LDS transpose-reduce: thread t<128 owns output (ch,p,q) = t and
//            dots s_row[64] with gx[q][64] via float4 LDS reads.
//
// NOTE: no __launch_bounds__ min-wave cap — forcing 64 VGPRs spilled the
// inner loop in round 4 (19.3 -> 43.4 us).

constexpr int N_ = 64;
constexpr int C_ = 256;
constexpr int H_ = 72;
constexpr int W_ = 72;
constexpr int HW_ = H_ * W_;
constexpr int CPW = 2;               // channels per wave
constexpr int NW  = 4;               // waves per block
constexpr int CPB = CPW * NW;        // 8 channels per block
constexpr int SPAD = 68;             // padded row length (floats)
constexpr int GYR = 40;              // gy rows incl. zero padding (max r+6 = 36)

__device__ __forceinline__ float Gfun(float u) {
    // Antiderivative of max(0, 1-|u|), clipped so G(-1)=0, G(1)=1.
    u = fminf(1.0f, fmaxf(-1.0f, u));
    return (u <= 0.0f) ? (0.5f * (u + 1.0f) * (u + 1.0f))
                       : (1.0f - 0.5f * (1.0f - u) * (1.0f - u));
}

__global__ __launch_bounds__(256)
void prroi_kernel(const float* __restrict__ feat,
                  const float* __restrict__ bb,
                  float* __restrict__ out) {
    __shared__ float gy_lds[GYR][4];              // rows j0.., zero past j1
    __shared__ float gx_lds[4][SPAD];
    __shared__ float s_lds[CPB * 4][SPAD];        // [(ch*4+p)][lane]

    const int bid = blockIdx.x;
    const int n   = bid & 63;          // interleave n across consecutive blocks
    const int cg  = bid >> 6;          // 0..31 channel-group
    const int tid = (int)threadIdx.x;
    const int w      = tid >> 6;
    const int lane   = tid & 63;
    const int coll   = lane & 31;      // column offset within ROI window
    const int parity = lane >> 5;      // row parity this lane handles

    const float bx = bb[n*4+0], by = bb[n*4+1], bw = bb[n*4+2], bh = bb[n*4+3];
    const float inv_s = 1.0f / 16.0f;
    const float x1 = bx*inv_s,        y1 = by*inv_s;
    const float x2 = (bx+bw)*inv_s,   y2 = (by+bh)*inv_s;
    const float binw = (x2-x1)*0.25f, binh = (y2-y1)*0.25f;

    // Support of the bilinear weights: i in (x1-1, x2+1); integer span <= 30.
    const int i0 = max((int)ceilf(x1 - 1.0f), 0);
    const int i1 = min((int)floorf(x2 + 1.0f), W_-1);
    const int j0 = max((int)ceilf(y1 - 1.0f), 0);
    const int j1 = min((int)floorf(y2 + 1.0f), H_-1);

    // ---- weight tables (once per block) ----
    if (tid < GYR * 4) {               // 40 rows x 4 bins (zeros past j1)
        const int r = tid >> 2, p = tid & 3;
        const int h = j0 + r;
        float v = 0.0f;
        if (h <= j1) {
            const float a = y1 + (float)p * binh, b = a + binh;
            v = Gfun(b - (float)h) - Gfun(a - (float)h);
        }
        gy_lds[r][p] = v;
    }
    {                                  // gx duplicated across both parities
        const int q = tid >> 6, l = tid & 63;
        const int col = i0 + (l & 31);
        float v = 0.0f;
        if (col <= i1) {
            const float a = x1 + (float)q * binw, b = a + binw;
            v = Gfun(b - (float)col) - Gfun(a - (float)col);
        }
        gx_lds[q][l] = v;
    }
    __syncthreads();

    // ---- phase 1: row-weighted column sums, 2 channels per wave ----
    // Inactive columns clamp to i1 and past-j1 rows clamp to j1: duplicate
    // reads of lines the wave already fetches (coalesced, no extra HBM).
    // Their contributions are zeroed by gx == 0 (phase 2) or gy == 0 (here).
    const int colc = min(i0 + coll, i1);
    const float* fb = feat + (size_t)(n*C_ + cg*CPB + w*CPW) * HW_;
    float s[CPW][4] = {};
    for (int h = j0 + parity; h <= j1; h += 8) {
        const int a0 = h*W_ + colc;                 // h <= j1 by loop condition
        const int a1 = min(h + 2, j1)*W_ + colc;
        const int a2 = min(h + 4, j1)*W_ + colc;
        const int a3 = min(h + 6, j1)*W_ + colc;
        float f[CPW][4];
        #pragma unroll
        for (int c = 0; c < CPW; ++c) {
            const float* fc = fb + c*HW_;
            f[c][0] = fc[a0]; f[c][1] = fc[a1]; f[c][2] = fc[a2]; f[c][3] = fc[a3];
        }
        const int r = h - j0;
        const float4 gy0 = *reinterpret_cast<const float4*>(&gy_lds[r    ][0]);
        const float4 gy1 = *reinterpret_cast<const float4*>(&gy_lds[r + 2][0]);
        const float4 gy2 = *reinterpret_cast<const float4*>(&gy_lds[r + 4][0]);
        const float4 gy3 = *reinterpret_cast<const float4*>(&gy_lds[r + 6][0]);
        #pragma unroll
        for (int c = 0; c < CPW; ++c) {
            s[c][0] = fmaf(gy0.x, f[c][0], s[c][0]);
            s[c][1] = fmaf(gy0.y, f[c][0], s[c][1]);
            s[c][2] = fmaf(gy0.z, f[c][0], s[c][2]);
            s[c][3] = fmaf(gy0.w, f[c][0], s[c][3]);
            s[c][0] = fmaf(gy1.x, f[c][1], s[c][0]);
            s[c][1] = fmaf(gy1.y, f[c][1], s[c][1]);
            s[c][2] = fmaf(gy1.z, f[c][1], s[c][2]);
            s[c][3] = fmaf(gy1.w, f[c][1], s[c][3]);
            s[c][0] = fmaf(gy2.x, f[c][2], s[c][0]);
            s[c][1] = fmaf(gy2.y, f[c][2], s[c][1]);
            s[c][2] = fmaf(gy2.z, f[c][2], s[c][2]);
            s[c][3] = fmaf(gy2.w, f[c][2], s[c][3]);
            s[c][0] = fmaf(gy3.x, f[c][3], s[c][0]);
            s[c][1] = fmaf(gy3.y, f[c][3], s[c][1]);
            s[c][2] = fmaf(gy3.z, f[c][3], s[c][2]);
            s[c][3] = fmaf(gy3.w, f[c][3], s[c][3]);
        }
    }
    #pragma unroll
    for (int c = 0; c < CPW; ++c)
        #pragma unroll
        for (int p = 0; p < 4; ++p)
            s_lds[(w*CPW + c)*4 + p][lane] = s[c][p];   // 64 consecutive cols: conflict-free
    __syncthreads();

    // ---- phase 2: one output per thread (tid < 128); out offset == tid ----
    if (tid < CPB * 16) {
        const int q = tid & 3;
        const int rowi = tid >> 2;               // (ch*4 + p), 0..31
        const float* srow = &s_lds[rowi][0];
        const float* gxr  = &gx_lds[q][0];
        float acc = 0.0f;
        #pragma unroll
        for (int i = 0; i < 16; ++i) {
            const float4 sv = *reinterpret_cast<const float4*>(srow + i*4);
            const float4 gv = *reinterpret_cast<const float4*>(gxr  + i*4);
            acc += sv.x*gv.x + sv.y*gv.y + sv.z*gv.z + sv.w*gv.w;
        }
        const float area = fmaxf(binw * binh, 0.0f);
        const float inv  = (area > 0.0f) ? (1.0f / fmaxf(area, 1e-12f)) : 0.0f;
        out[(size_t)(n*C_ + cg*CPB) * 16 + tid] = acc * inv;
    }
}

extern "C" void kernel_launch(void* const* d_in, const int* in_sizes, int n_in,
                              void* d_out, int out_size, void* d_ws, size_t ws_size,
                              hipStream_t stream) {
    const float* feat = (const float*)d_in[0];
    const float* bb   = (const float*)d_in[1];
    float* outp       = (float*)d_out;
    prroi_kernel<<<dim3(N_ * (C_ / CPB)), dim3(256), 0, stream>>>(feat, bb, outp);
}

// Round 7
// 15.886 us; speedup vs baseline: 2.7312x; 1.0713x over previous
//
#include <hip/hip_runtime.h>

// PrRoI pooling (exact bilinear-integral) for feat [64,256,72,72] f32,
// bb [64,4] (x,y,w,h image coords, stride 16), out [64,256,4,4] f32.
//
// Separable weights: out[p][q] = (1/area) * sum_w gx[q][w] * sum_h gy[p][h] * f[h][w].
// Block = 256 threads (4 waves) = one n x 8 channels; grid 2048 (8 blocks/CU).
// n = bid & 63 so consecutively-dispatched blocks carry different ROI sizes.
//   phase 1: each wave does 2 channels; lane = (col 0..31, row-parity 0..1);
//            h-loop FULLY UNROLLED to 15 fixed chunks (row span <= 30, so
//            <= 15 rows per parity): all 30 global loads issue back-to-back
//            (one exposed HBM latency round per wave), rows past j1 clamp to
//            the j1 row (same cache line -> L1 hit, no extra HBM) and get
//            exact-zero gy weights from the zero-padded table.
//   phase 2: LDS transpose-reduce: thread t<128 owns output (ch,p,q) = t and
//            dots s_row[64] with gx[q][64] via float4 LDS reads.
//
// NOTE: no __launch_bounds__ min-wave cap — forcing 64 VGPRs spilled the
// inner loop in round 4 (19.3 -> 43.4 us).

constexpr int N_ = 64;
constexpr int C_ = 256;
constexpr int H_ = 72;
constexpr int W_ = 72;
constexpr int HW_ = H_ * W_;
constexpr int CPW = 2;               // channels per wave
constexpr int NW  = 4;               // waves per block
constexpr int CPB = CPW * NW;        // 8 channels per block
constexpr int SPAD = 68;             // padded row length (floats)
constexpr int GYR = 32;              // gy rows incl. zero padding (max r = 29)
constexpr int KCH = 15;              // row chunks per parity (span <= 30)

__device__ __forceinline__ float Gfun(float u) {
    // Antiderivative of max(0, 1-|u|), clipped so G(-1)=0, G(1)=1.
    u = fminf(1.0f, fmaxf(-1.0f, u));
    return (u <= 0.0f) ? (0.5f * (u + 1.0f) * (u + 1.0f))
                       : (1.0f - 0.5f * (1.0f - u) * (1.0f - u));
}

__global__ __launch_bounds__(256)
void prroi_kernel(const float* __restrict__ feat,
                  const float* __restrict__ bb,
                  float* __restrict__ out) {
    __shared__ float gy_lds[GYR][4];              // rows j0.., zero past j1
    __shared__ float gx_lds[4][SPAD];
    __shared__ float s_lds[CPB * 4][SPAD];        // [(ch*4+p)][lane]

    const int bid = blockIdx.x;
    const int n   = bid & 63;          // interleave n across consecutive blocks
    const int cg  = bid >> 6;          // 0..31 channel-group
    const int tid = (int)threadIdx.x;
    const int w      = tid >> 6;
    const int lane   = tid & 63;
    const int coll   = lane & 31;      // column offset within ROI window
    const int parity = lane >> 5;      // row parity this lane handles

    const float bx = bb[n*4+0], by = bb[n*4+1], bw = bb[n*4+2], bh = bb[n*4+3];
    const float inv_s = 1.0f / 16.0f;
    const float x1 = bx*inv_s,        y1 = by*inv_s;
    const float x2 = (bx+bw)*inv_s,   y2 = (by+bh)*inv_s;
    const float binw = (x2-x1)*0.25f, binh = (y2-y1)*0.25f;

    // Support of the bilinear weights: i in (x1-1, x2+1); integer span <= 30.
    const int i0 = max((int)ceilf(x1 - 1.0f), 0);
    const int i1 = min((int)floorf(x2 + 1.0f), W_-1);
    const int j0 = max((int)ceilf(y1 - 1.0f), 0);
    const int j1 = min((int)floorf(y2 + 1.0f), H_-1);

    // ---- weight tables (once per block) ----
    if (tid < GYR * 4) {               // 32 rows x 4 bins (zeros past j1)
        const int r = tid >> 2, p = tid & 3;
        const int h = j0 + r;
        float v = 0.0f;
        if (h <= j1) {
            const float a = y1 + (float)p * binh, b = a + binh;
            v = Gfun(b - (float)h) - Gfun(a - (float)h);
        }
        gy_lds[r][p] = v;
    }
    {                                  // gx duplicated across both parities
        const int q = tid >> 6, l = tid & 63;
        const int col = i0 + (l & 31);
        float v = 0.0f;
        if (col <= i1) {
            const float a = x1 + (float)q * binw, b = a + binw;
            v = Gfun(b - (float)col) - Gfun(a - (float)col);
        }
        gx_lds[q][l] = v;
    }
    __syncthreads();

    // ---- phase 1: row-weighted column sums, one HBM round ----
    // Inactive columns clamp to i1; rows past j1 clamp to the j1 row (dup
    // loads of already-fetched lines). Contributions beyond the ROI are
    // zeroed by gx == 0 (phase 2) or gy == 0 (here).
    const int colc = min(i0 + coll, i1);
    const float* fb = feat + (size_t)(n*C_ + cg*CPB + w*CPW) * HW_;

    int aoff[KCH];
    #pragma unroll
    for (int k = 0; k < KCH; ++k) {
        const int h = j0 + parity + 2*k;
        aoff[k] = min(h, j1)*W_ + colc;
    }
    float f[CPW][KCH];
    #pragma unroll
    for (int c = 0; c < CPW; ++c) {
        const float* fc = fb + c*HW_;
        #pragma unroll
        for (int k = 0; k < KCH; ++k)
            f[c][k] = fc[aoff[k]];               // 30 independent loads in flight
    }

    float s[CPW][4] = {};
    #pragma unroll
    for (int k = 0; k < KCH; ++k) {
        const float4 gy = *reinterpret_cast<const float4*>(&gy_lds[parity + 2*k][0]);
        #pragma unroll
        for (int c = 0; c < CPW; ++c) {
            s[c][0] = fmaf(gy.x, f[c][k], s[c][0]);
            s[c][1] = fmaf(gy.y, f[c][k], s[c][1]);
            s[c][2] = fmaf(gy.z, f[c][k], s[c][2]);
            s[c][3] = fmaf(gy.w, f[c][k], s[c][3]);
        }
    }

    #pragma unroll
    for (int c = 0; c < CPW; ++c)
        #pragma unroll
        for (int p = 0; p < 4; ++p)
            s_lds[(w*CPW + c)*4 + p][lane] = s[c][p];   // 64 consecutive cols: conflict-free
    __syncthreads();

    // ---- phase 2: one output per thread (tid < 128); out offset == tid ----
    if (tid < CPB * 16) {
        const int q = tid & 3;
        const int rowi = tid >> 2;               // (ch*4 + p), 0..31
        const float* srow = &s_lds[rowi][0];
        const float* gxr  = &gx_lds[q][0];
        float acc = 0.0f;
        #pragma unroll
        for (int i = 0; i < 16; ++i) {
            const float4 sv = *reinterpret_cast<const float4*>(srow + i*4);
            const float4 gv = *reinterpret_cast<const float4*>(gxr  + i*4);
            acc += sv.x*gv.x + sv.y*gv.y + sv.z*gv.z + sv.w*gv.w;
        }
        const float area = fmaxf(binw * binh, 0.0f);
        const float inv  = (area > 0.0f) ? (1.0f / fmaxf(area, 1e-12f)) : 0.0f;
        out[(size_t)(n*C_ + cg*CPB) * 16 + tid] = acc * inv;
    }
}

extern "C" void kernel_launch(void* const* d_in, const int* in_sizes, int n_in,
                              void* d_out, int out_size, void* d_ws, size_t ws_size,
                              hipStream_t stream) {
    const float* feat = (const float*)d_in[0];
    const float* bb   = (const float*)d_in[1];
    float* outp       = (float*)d_out;
    prroi_kernel<<<dim3(N_ * (C_ / CPB)), dim3(256), 0, stream>>>(feat, bb, outp);
}

// Round 8
// 15.616 us; speedup vs baseline: 2.7786x; 1.0173x over previous
//
#include <hip/hip_runtime.h>

// PrRoI pooling (exact bilinear-integral) for feat [64,256,72,72] f32,
// bb [64,4] (x,y,w,h image coords, stride 16), out [64,256,4,4] f32.
//
// Separable weights: out[p][q] = (1/area) * sum_w gx[q][w] * sum_h gy[p][h] * f[h][w].
// Block = 256 threads (4 waves) = one n x 8 channels; grid 2048 (8 blocks/CU).
//
// Block->(n,cg) mapping: n = bid >> 5, cg = bid & 31. CUs receive blocks at
// stride ~256 (round-robin over 8 XCDs x 32 CUs), so a CU's 8 blocks have
// n = const + 8k (8 DIFFERENT ROI sizes) -> per-CU work averages out.
// (Round 6/7 used n = bid & 63, which gave every CU 8 copies of the SAME n:
// worst-case CU work ~2.2x average -> straggler tail.)
//
//   phase 1: each wave does 2 channels; lane = (col 0..31, row-parity 0..1);
//            h-loop FULLY UNROLLED to 15 fixed chunks (row span <= 30):
//            all 30 global loads issue back-to-back (one exposed HBM latency
//            round per wave); rows past j1 clamp to the j1 row and columns
//            past i1 clamp to i1 (duplicate reads of already-fetched lines,
//            no extra HBM); out-of-ROI terms get exact-zero weights.
//   phase 2: LDS transpose-reduce: thread t<128 owns output (ch,p,q) = t and
//            dots s_row[64] with gx[q][64] via float4 LDS reads.
//
// NOTE: no __launch_bounds__ min-wave cap — forcing 64 VGPRs spilled the
// inner loop in round 4 (19.3 -> 43.4 us).

constexpr int N_ = 64;
constexpr int C_ = 256;
constexpr int H_ = 72;
constexpr int W_ = 72;
constexpr int HW_ = H_ * W_;
constexpr int CPW = 2;               // channels per wave
constexpr int NW  = 4;               // waves per block
constexpr int CPB = CPW * NW;        // 8 channels per block
constexpr int SPAD = 68;             // padded row length (floats)
constexpr int GYR = 32;              // gy rows incl. zero padding (max r = 29)
constexpr int KCH = 15;              // row chunks per parity (span <= 30)

__device__ __forceinline__ float Gfun(float u) {
    // Antiderivative of max(0, 1-|u|), clipped so G(-1)=0, G(1)=1.
    u = fminf(1.0f, fmaxf(-1.0f, u));
    return (u <= 0.0f) ? (0.5f * (u + 1.0f) * (u + 1.0f))
                       : (1.0f - 0.5f * (1.0f - u) * (1.0f - u));
}

__global__ __launch_bounds__(256)
void prroi_kernel(const float* __restrict__ feat,
                  const float* __restrict__ bb,
                  float* __restrict__ out) {
    __shared__ float gy_lds[GYR][4];              // rows j0.., zero past j1
    __shared__ float gx_lds[4][SPAD];
    __shared__ float s_lds[CPB * 4][SPAD];        // [(ch*4+p)][lane]

    const int bid = blockIdx.x;
    const int n   = bid >> 5;          // 8 distinct n per CU (stride-256 sampling)
    const int cg  = bid & 31;          // 0..31 channel-group
    const int tid = (int)threadIdx.x;
    const int w      = tid >> 6;
    const int lane   = tid & 63;
    const int coll   = lane & 31;      // column offset within ROI window
    const int parity = lane >> 5;      // row parity this lane handles

    const float bx = bb[n*4+0], by = bb[n*4+1], bw = bb[n*4+2], bh = bb[n*4+3];
    const float inv_s = 1.0f / 16.0f;
    const float x1 = bx*inv_s,        y1 = by*inv_s;
    const float x2 = (bx+bw)*inv_s,   y2 = (by+bh)*inv_s;
    const float binw = (x2-x1)*0.25f, binh = (y2-y1)*0.25f;

    // Support of the bilinear weights: i in (x1-1, x2+1); integer span <= 30.
    const int i0 = max((int)ceilf(x1 - 1.0f), 0);
    const int i1 = min((int)floorf(x2 + 1.0f), W_-1);
    const int j0 = max((int)ceilf(y1 - 1.0f), 0);
    const int j1 = min((int)floorf(y2 + 1.0f), H_-1);

    // ---- weight tables (once per block) ----
    if (tid < GYR * 4) {               // 32 rows x 4 bins (zeros past j1)
        const int r = tid >> 2, p = tid & 3;
        const int h = j0 + r;
        float v = 0.0f;
        if (h <= j1) {
            const float a = y1 + (float)p * binh, b = a + binh;
            v = Gfun(b - (float)h) - Gfun(a - (float)h);
        }
        gy_lds[r][p] = v;
    }
    {                                  // gx duplicated across both parities
        const int q = tid >> 6, l = tid & 63;
        const int col = i0 + (l & 31);
        float v = 0.0f;
        if (col <= i1) {
            const float a = x1 + (float)q * binw, b = a + binw;
            v = Gfun(b - (float)col) - Gfun(a - (float)col);
        }
        gx_lds[q][l] = v;
    }
    __syncthreads();

    // ---- phase 1: row-weighted column sums, one HBM round ----
    const int colc = min(i0 + coll, i1);
    const float* fb = feat + (size_t)(n*C_ + cg*CPB + w*CPW) * HW_;

    int aoff[KCH];
    #pragma unroll
    for (int k = 0; k < KCH; ++k) {
        const int h = j0 + parity + 2*k;
        aoff[k] = min(h, j1)*W_ + colc;
    }
    float f[CPW][KCH];
    #pragma unroll
    for (int c = 0; c < CPW; ++c) {
        const float* fc = fb + c*HW_;
        #pragma unroll
        for (int k = 0; k < KCH; ++k)
            f[c][k] = fc[aoff[k]];               // 30 independent loads in flight
    }

    float s[CPW][4] = {};
    #pragma unroll
    for (int k = 0; k < KCH; ++k) {
        const float4 gy = *reinterpret_cast<const float4*>(&gy_lds[parity + 2*k][0]);
        #pragma unroll
        for (int c = 0; c < CPW; ++c) {
            s[c][0] = fmaf(gy.x, f[c][k], s[c][0]);
            s[c][1] = fmaf(gy.y, f[c][k], s[c][1]);
            s[c][2] = fmaf(gy.z, f[c][k], s[c][2]);
            s[c][3] = fmaf(gy.w, f[c][k], s[c][3]);
        }
    }

    #pragma unroll
    for (int c = 0; c < CPW; ++c)
        #pragma unroll
        for (int p = 0; p < 4; ++p)
            s_lds[(w*CPW + c)*4 + p][lane] = s[c][p];   // 64 consecutive cols: conflict-free
    __syncthreads();

    // ---- phase 2: one output per thread (tid < 128); out offset == tid ----
    if (tid < CPB * 16) {
        const int q = tid & 3;
        const int rowi = tid >> 2;               // (ch*4 + p), 0..31
        const float* srow = &s_lds[rowi][0];
        const float* gxr  = &gx_lds[q][0];
        float acc = 0.0f;
        #pragma unroll
        for (int i = 0; i < 16; ++i) {
            const float4 sv = *reinterpret_cast<const float4*>(srow + i*4);
            const float4 gv = *reinterpret_cast<const float4*>(gxr  + i*4);
            acc += sv.x*gv.x + sv.y*gv.y + sv.z*gv.z + sv.w*gv.w;
        }
        const float area = fmaxf(binw * binh, 0.0f);
        const float inv  = (area > 0.0f) ? (1.0f / fmaxf(area, 1e-12f)) : 0.0f;
        out[(size_t)(n*C_ + cg*CPB) * 16 + tid] = acc * inv;
    }
}

extern "C" void kernel_launch(void* const* d_in, const int* in_sizes, int n_in,
                              void* d_out, int out_size, void* d_ws, size_t ws_size,
                              hipStream_t stream) {
    const float* feat = (const float*)d_in[0];
    const float* bb   = (const float*)d_in[1];
    float* outp       = (float*)d_out;
    prroi_kernel<<<dim3(N_ * (C_ / CPB)), dim3(256), 0, stream>>>(feat, bb, outp);
}